// Round 4
// baseline (634.692 us; speedup 1.0000x reference)
//
#include <hip/hip_runtime.h>
#include <stdint.h>

typedef __attribute__((ext_vector_type(8))) short short8;
typedef __attribute__((ext_vector_type(4))) float floatx4;

__device__ __forceinline__ float b2f(uint16_t u) {
  union { uint32_t i; float f; } v; v.i = ((uint32_t)u) << 16; return v.f;
}
__device__ __forceinline__ uint16_t f2b(float f) {
  union { float f; uint32_t i; } v; v.f = f;
  uint32_t r = v.i + 0x7FFFu + ((v.i >> 16) & 1u);
  return (uint16_t)(r >> 16);
}

// ---- input dtype detection -------------------------------------------------
// freqs_cos[0..1] == 1.0 exactly. fp32 buffer first dword = 0x3F800000;
// bf16 buffer first dword = 0x3F803F80. flag=1 => fp32 inputs (and fp32 output).
__global__ void detect_dtype(const uint32_t* __restrict__ freqs, int* __restrict__ flag) {
  *flag = (freqs[0] == 0x3F800000u) ? 1 : 0;
}

// Convert n8*8 elements to bf16 (copy if already bf16).
__global__ __launch_bounds__(256) void cvt_bf16(const void* __restrict__ src,
                                                uint16_t* __restrict__ dst,
                                                int n8, const int* __restrict__ flag) {
  const int idx = blockIdx.x * 256 + threadIdx.x;
  if (idx >= n8) return;
  if (*flag) {
    const float4* s = (const float4*)src;
    float4 a = s[2 * idx], b = s[2 * idx + 1];
    uint16_t o[8] = {f2b(a.x), f2b(a.y), f2b(a.z), f2b(a.w),
                     f2b(b.x), f2b(b.y), f2b(b.z), f2b(b.w)};
    ((uint4*)dst)[idx] = *(const uint4*)o;
  } else {
    ((uint4*)dst)[idx] = ((const uint4*)src)[idx];
  }
}

// One launch for all 6 small vectors (bias/norm weights).
__global__ __launch_bounds__(256) void cvt_small6(
    const void* s0, uint16_t* d0, const void* s1, uint16_t* d1,
    const void* s2, uint16_t* d2, const void* s3, uint16_t* d3,
    const void* s4, uint16_t* d4, const void* s5, uint16_t* d5,
    const int* __restrict__ flag) {
  const void* srcs[6] = {s0, s1, s2, s3, s4, s5};
  uint16_t* dsts[6] = {d0, d1, d2, d3, d4, d5};
  const int lens[6] = {1536, 1536, 576, 512, 4096, 2048};
  const int b = blockIdx.x;
  const int n8 = lens[b] / 8;
  const int f = *flag;
  for (int i = threadIdx.x; i < n8; i += 256) {
    if (f) {
      const float4* s = (const float4*)srcs[b];
      float4 a = s[2 * i], c = s[2 * i + 1];
      uint16_t o[8] = {f2b(a.x), f2b(a.y), f2b(a.z), f2b(a.w),
                       f2b(c.x), f2b(c.y), f2b(c.z), f2b(c.w)};
      ((uint4*)dsts[b])[i] = *(const uint4*)o;
    } else {
      ((uint4*)dsts[b])[i] = ((const uint4*)srcs[b])[i];
    }
  }
}

// Gather+convert the 16 heads' nope rows (first 128 of each 192) of wq_b
// into packed [2048,1536] bf16 weight + packed bias.
__global__ __launch_bounds__(192) void convert_pack_wq(
    const void* __restrict__ w, const void* __restrict__ b,
    uint16_t* __restrict__ wp, uint16_t* __restrict__ bp,
    const int* __restrict__ flag) {
  const int row = blockIdx.x;                       // 0..2047
  const int src = (row >> 7) * 192 + (row & 127);   // head*192 + sub
  const int t = threadIdx.x;                        // 0..191 (16B chunks of 1536 elems)
  if (*flag) {
    const float4* s = (const float4*)w + (size_t)src * 384;
    float4 a = s[2 * t], c = s[2 * t + 1];
    uint16_t o[8] = {f2b(a.x), f2b(a.y), f2b(a.z), f2b(a.w),
                     f2b(c.x), f2b(c.y), f2b(c.z), f2b(c.w)};
    ((uint4*)(wp + (size_t)row * 1536))[t] = *(const uint4*)o;
    if (t == 0) bp[row] = f2b(((const float*)b)[src]);
  } else {
    ((uint4*)(wp + (size_t)row * 1536))[t] = ((const uint4*)w)[(size_t)src * 192 + t];
    if (t == 0) bp[row] = ((const uint16_t*)b)[src];
  }
}

// async global->LDS, 16B per lane. Dest = wave-uniform base + lane*16 (m97/m104).
__device__ __forceinline__ void async_copy16(const uint16_t* g, uint16_t* l) {
  __builtin_amdgcn_global_load_lds(
      (const __attribute__((address_space(1))) void*)g,
      (__attribute__((address_space(3))) void*)l,
      16, 0, 0);
}

// C[M,N] = A[M,K] @ W[N,K]^T + bias[N]; bf16 in, fp32 accum (m97 structure).
// Output: bf16 to C, unless (f32flag && *f32flag) -> fp32 to C32.
__global__ __launch_bounds__(256) void gemm_bt_bias(
    const uint16_t* __restrict__ A, const uint16_t* __restrict__ W,
    const uint16_t* __restrict__ bias, uint16_t* __restrict__ C,
    float* __restrict__ C32, const int* __restrict__ f32flag,
    int M, int N, int K)
{
  (void)M;
  __shared__ uint16_t As[128 * 64];
  __shared__ uint16_t Bs[128 * 64];
  const int tid  = threadIdx.x;
  const int lane = tid & 63;
  const int wave = tid >> 6;
  const int wm = (wave >> 1) * 64;
  const int wn = (wave & 1) * 64;
  const int bm = blockIdx.y * 128;
  const int bn = blockIdx.x * 128;
  const int ml = lane & 15;
  const int quad = lane >> 4;

  floatx4 acc[4][4];
#pragma unroll
  for (int i = 0; i < 4; ++i)
#pragma unroll
    for (int j = 0; j < 4; ++j)
      acc[i][j] = (floatx4){0.f, 0.f, 0.f, 0.f};

  const int srow = tid >> 3;        // 0..31
  const int scol = (tid & 7) * 8;   // 0..56
  const uint16_t* Ag = A + (size_t)(bm + srow) * K + scol;
  const uint16_t* Wg = W + (size_t)(bn + srow) * K + scol;

  for (int k0 = 0; k0 < K; k0 += 64) {
#pragma unroll
    for (int r = 0; r < 4; ++r) {
      async_copy16(Ag + (size_t)r * 32 * K + k0, &As[r * 2048 + tid * 8]);
      async_copy16(Wg + (size_t)r * 32 * K + k0, &Bs[r * 2048 + tid * 8]);
    }
    __syncthreads();
#pragma unroll
    for (int ks = 0; ks < 2; ++ks) {
      short8 a[4], b[4];
#pragma unroll
      for (int i = 0; i < 4; ++i)
        a[i] = *(const short8*)&As[(wm + i * 16 + ml) * 64 + ks * 32 + quad * 8];
#pragma unroll
      for (int j = 0; j < 4; ++j)
        b[j] = *(const short8*)&Bs[(wn + j * 16 + ml) * 64 + ks * 32 + quad * 8];
#pragma unroll
      for (int i = 0; i < 4; ++i)
#pragma unroll
        for (int j = 0; j < 4; ++j)
          acc[i][j] = __builtin_amdgcn_mfma_f32_16x16x32_bf16(a[i], b[j], acc[i][j], 0, 0, 0);
    }
    __syncthreads();
  }

  // C/D layout: col = lane&15, row = quad*4 + reg (m89/m91)
  const bool f32out = (f32flag != nullptr) && (*f32flag != 0);
#pragma unroll
  for (int j = 0; j < 4; ++j) {
    const int col = bn + wn + j * 16 + ml;
    const float bv = b2f(bias[col]);
#pragma unroll
    for (int i = 0; i < 4; ++i) {
      const int row0 = bm + wm + i * 16 + quad * 4;
      if (f32out) {
#pragma unroll
        for (int r = 0; r < 4; ++r)
          C32[(size_t)(row0 + r) * N + col] = acc[i][j][r] + bv;
      } else {
#pragma unroll
        for (int r = 0; r < 4; ++r)
          C[(size_t)(row0 + r) * N + col] = f2b(acc[i][j][r] + bv);
      }
    }
  }
}

template <int L>
__global__ __launch_bounds__(256) void rmsnorm_inplace(uint16_t* __restrict__ x,
                                                       const uint16_t* __restrict__ w)
{
  constexpr int NV = L / 8;
  __shared__ float red[256];
  const int t = threadIdx.x;
  uint16_t* xr = x + (size_t)blockIdx.x * L;
  float lv[8];
  float ss = 0.f;
  if (t < NV) {
    uint4 v = ((const uint4*)xr)[t];
    const uint16_t* u = (const uint16_t*)&v;
#pragma unroll
    for (int i = 0; i < 8; ++i) { lv[i] = b2f(u[i]); ss += lv[i] * lv[i]; }
  }
  red[t] = ss;
  __syncthreads();
  for (int s = 128; s > 0; s >>= 1) {
    if (t < s) red[t] += red[t + s];
    __syncthreads();
  }
  const float inv = rsqrtf(red[0] / (float)L + 1.1920929e-7f);
  if (t < NV) {
    uint4 wv = ((const uint4*)w)[t];
    const uint16_t* wu = (const uint16_t*)&wv;
    uint16_t ob[8];
#pragma unroll
    for (int i = 0; i < 8; ++i) ob[i] = f2b(lv[i] * inv * b2f(wu[i]));
    ((uint4*)xr)[t] = *(const uint4*)ob;
  }
}

// Per-token head-vs-head attention; RoPE drops out of softmax (k_pe broadcast
// over g => per-h additive constant). qn:[T,2048] kvb:[T,4096] out:[T,2048]
__global__ __launch_bounds__(256) void attn_kernel(
    const uint16_t* __restrict__ qn,
    const uint16_t* __restrict__ kvb,
    uint16_t* __restrict__ outp)
{
  __shared__ uint16_t q_s[2048];
  __shared__ uint16_t kv_s[16 * 264];
  __shared__ float s_at[256];
  const int t = blockIdx.x;
  const int tid = threadIdx.x;

  ((uint4*)q_s)[tid] = ((const uint4*)(qn + (size_t)t * 2048))[tid];
  {
    const uint4* src = (const uint4*)(kvb + (size_t)t * 4096);
#pragma unroll
    for (int r = 0; r < 2; ++r) {
      int c = tid + r * 256;
      ((uint4*)kv_s)[(c >> 5) * 33 + (c & 31)] = src[c];
    }
  }
  __syncthreads();

  const int h = tid >> 4, g = tid & 15;
  float sc = 0.f;
  const uint4* qh = (const uint4*)(q_s + h * 128);
  const uint4* kg = (const uint4*)(kv_s + g * 264);
#pragma unroll
  for (int c = 0; c < 16; ++c) {
    uint4 qa = qh[c], kb = kg[c];
    const uint16_t* qa_u = (const uint16_t*)&qa;
    const uint16_t* kb_u = (const uint16_t*)&kb;
#pragma unroll
    for (int i = 0; i < 8; ++i) sc += b2f(qa_u[i]) * b2f(kb_u[i]);
  }
  sc *= 0.07216878364870323f;   // (128+64)^-0.5
  float mx = sc;
#pragma unroll
  for (int o = 8; o >= 1; o >>= 1) mx = fmaxf(mx, __shfl_xor(mx, o, 16));
  const float e = __expf(sc - mx);
  float sum = e;
#pragma unroll
  for (int o = 8; o >= 1; o >>= 1) sum += __shfl_xor(sum, o, 16);
  s_at[tid] = e / sum;
  __syncthreads();

  float acc[8] = {0.f, 0.f, 0.f, 0.f, 0.f, 0.f, 0.f, 0.f};
  const int c8 = tid & 15;
#pragma unroll
  for (int gg = 0; gg < 16; ++gg) {
    const float a = s_at[h * 16 + gg];
    uint4 vv = *(const uint4*)(kv_s + gg * 264 + 128 + c8 * 8);
    const uint16_t* vu = (const uint16_t*)&vv;
#pragma unroll
    for (int i = 0; i < 8; ++i) acc[i] += a * b2f(vu[i]);
  }
  uint16_t ob[8];
#pragma unroll
  for (int i = 0; i < 8; ++i) ob[i] = f2b(acc[i]);
  *(uint4*)(outp + (size_t)t * 2048 + h * 128 + c8 * 8) = *(const uint4*)ob;
}

extern "C" void kernel_launch(void* const* d_in, const int* in_sizes, int n_in,
                              void* d_out, int out_size, void* d_ws, size_t ws_size,
                              hipStream_t stream)
{
  (void)in_sizes; (void)n_in; (void)out_size; (void)ws_size;
  const void* x_r       = d_in[0];
  const void* freqs_cos = d_in[1];   // used only for dtype detection
  const void* wq_a_w_r  = d_in[3];
  const void* wq_a_b_r  = d_in[4];
  const void* q_norm_r  = d_in[5];
  const void* wq_b_w_r  = d_in[6];
  const void* wq_b_b_r  = d_in[7];
  const void* wkv_a_w_r = d_in[8];
  const void* wkv_a_b_r = d_in[9];
  const void* kv_norm_r = d_in[10];
  const void* wkv_b_w_r = d_in[11];
  const void* wkv_b_b_r = d_in[12];
  const void* wo_w_r    = d_in[13];
  const void* wo_b_r    = d_in[14];

  char* ws = (char*)d_ws;
  uint16_t* cx     = (uint16_t*)(ws);                 // 8192x2048 bf16; reused as attn later
  uint16_t* cwq_a  = (uint16_t*)(ws + 33554432);      // 1536x2048
  uint16_t* wpack  = (uint16_t*)(ws + 39845888);      // 2048x1536
  uint16_t* cwkv_a = (uint16_t*)(ws + 46137344);      // 576x2048
  uint16_t* cwkv_b = (uint16_t*)(ws + 48496640);      // 4096x512
  uint16_t* cwo    = (uint16_t*)(ws + 52690944);      // 2048x2048
  char*     smallb = (ws + 61079552);                 // small vectors + flag
  uint16_t* bq_a   = (uint16_t*)(smallb);             // 1536
  uint16_t* qnorm  = (uint16_t*)(smallb + 4096);      // 1536
  uint16_t* bkv_a  = (uint16_t*)(smallb + 8192);      // 576
  uint16_t* kvnorm = (uint16_t*)(smallb + 12288);     // 512
  uint16_t* bkv_b  = (uint16_t*)(smallb + 16384);     // 4096
  uint16_t* bwo    = (uint16_t*)(smallb + 24576);     // 2048
  uint16_t* bpack  = (uint16_t*)(smallb + 32768);     // 2048
  int*      flag   = (int*)(smallb + 40960);
  uint16_t* qa     = (uint16_t*)(ws + 61145088);      // 8192x1536
  uint16_t* kva    = (uint16_t*)(ws + 86310912);      // 8192x512
  uint16_t* qn     = (uint16_t*)(ws + 94699520);      // 8192x2048
  uint16_t* kvb    = (uint16_t*)(ws + 128253952);     // 8192x4096  (end ~186 MiB)
  uint16_t* attn   = cx;                              // cx dead after GEMMs 1-2

  detect_dtype<<<1, 1, 0, stream>>>((const uint32_t*)freqs_cos, flag);
  cvt_bf16<<<8192, 256, 0, stream>>>(x_r,       cx,     2097152, flag);
  cvt_bf16<<<1536, 256, 0, stream>>>(wq_a_w_r,  cwq_a,  393216,  flag);
  cvt_bf16<<<576,  256, 0, stream>>>(wkv_a_w_r, cwkv_a, 147456,  flag);
  cvt_bf16<<<1024, 256, 0, stream>>>(wkv_b_w_r, cwkv_b, 262144,  flag);
  cvt_bf16<<<2048, 256, 0, stream>>>(wo_w_r,    cwo,    524288,  flag);
  cvt_small6<<<6, 256, 0, stream>>>(wq_a_b_r, bq_a, q_norm_r, qnorm,
                                    wkv_a_b_r, bkv_a, kv_norm_r, kvnorm,
                                    wkv_b_b_r, bkv_b, wo_b_r, bwo, flag);
  convert_pack_wq<<<2048, 192, 0, stream>>>(wq_b_w_r, wq_b_b_r, wpack, bpack, flag);

  gemm_bt_bias<<<dim3(12, 64), 256, 0, stream>>>(cx,   cwq_a,  bq_a,  qa,  nullptr, nullptr, 8192, 1536, 2048);
  gemm_bt_bias<<<dim3(4, 64),  256, 0, stream>>>(cx,   cwkv_a, bkv_a, kva, nullptr, nullptr, 8192, 512,  2048);
  rmsnorm_inplace<1536><<<8192, 256, 0, stream>>>(qa,  qnorm);
  rmsnorm_inplace<512> <<<8192, 256, 0, stream>>>(kva, kvnorm);
  gemm_bt_bias<<<dim3(16, 64), 256, 0, stream>>>(qa,   wpack,  bpack, qn,  nullptr, nullptr, 8192, 2048, 1536);
  gemm_bt_bias<<<dim3(32, 64), 256, 0, stream>>>(kva,  cwkv_b, bkv_b, kvb, nullptr, nullptr, 8192, 4096, 512);
  attn_kernel<<<8192, 256, 0, stream>>>(qn, kvb, attn);
  // Final GEMM: fp32 output when inputs were fp32 (reference output dtype), bf16 otherwise.
  gemm_bt_bias<<<dim3(16, 64), 256, 0, stream>>>(attn, cwo, bwo,
                                                 (uint16_t*)d_out, (float*)d_out, flag,
                                                 8192, 2048, 2048);
}

// Round 5
// 559.670 us; speedup vs baseline: 1.1340x; 1.1340x over previous
//
#include <hip/hip_runtime.h>
#include <stdint.h>

typedef __attribute__((ext_vector_type(8))) short short8;
typedef __attribute__((ext_vector_type(4))) float floatx4;

// Inputs are fp32, output fp32 (confirmed on-device R3: detect flag fired fp32;
// fp32 d_out write passed R4).

__device__ __forceinline__ float b2f(uint16_t u) {
  union { uint32_t i; float f; } v; v.i = ((uint32_t)u) << 16; return v.f;
}
__device__ __forceinline__ uint16_t f2b(float f) {
  union { float f; uint32_t i; } v; v.f = f;
  uint32_t r = v.i + 0x7FFFu + ((v.i >> 16) & 1u);
  return (uint16_t)(r >> 16);
}

// fp32 -> bf16, 8 elems/thread.
__global__ __launch_bounds__(256) void cvt_w(const float* __restrict__ src,
                                             uint16_t* __restrict__ dst, int n8) {
  const int idx = blockIdx.x * 256 + threadIdx.x;
  if (idx >= n8) return;
  const float4* s = (const float4*)src;
  float4 a = s[2 * idx], b = s[2 * idx + 1];
  uint16_t o[8] = {f2b(a.x), f2b(a.y), f2b(a.z), f2b(a.w),
                   f2b(b.x), f2b(b.y), f2b(b.z), f2b(b.w)};
  ((uint4*)dst)[idx] = *(const uint4*)o;
}

// All 6 small vectors in one launch (blockIdx = segment).
__global__ __launch_bounds__(256) void cvt_small6(
    const float* s0, uint16_t* d0, const float* s1, uint16_t* d1,
    const float* s2, uint16_t* d2, const float* s3, uint16_t* d3,
    const float* s4, uint16_t* d4, const float* s5, uint16_t* d5) {
  const float* srcs[6] = {s0, s1, s2, s3, s4, s5};
  uint16_t* dsts[6] = {d0, d1, d2, d3, d4, d5};
  const int lens[6] = {1536, 512, 1536, 512, 4096, 2048};
  const int b = blockIdx.x;
  const int n8 = lens[b] / 8;
  for (int i = threadIdx.x; i < n8; i += 256) {
    const float4* s = (const float4*)srcs[b];
    float4 a = s[2 * i], c = s[2 * i + 1];
    uint16_t o[8] = {f2b(a.x), f2b(a.y), f2b(a.z), f2b(a.w),
                     f2b(c.x), f2b(c.y), f2b(c.z), f2b(c.w)};
    ((uint4*)dsts[b])[i] = *(const uint4*)o;
  }
}

// Gather+convert the 16 heads' nope rows (first 128 of each 192) of wq_b
// into packed [2048,1536] bf16 weight + packed bias. fp32 source.
__global__ __launch_bounds__(192) void pack_wq(
    const float* __restrict__ w, const float* __restrict__ b,
    uint16_t* __restrict__ wp, uint16_t* __restrict__ bp) {
  const int row = blockIdx.x;                       // 0..2047
  const int src = (row >> 7) * 192 + (row & 127);   // head*192 + sub
  const int t = threadIdx.x;                        // 0..191
  const float4* s = (const float4*)w + (size_t)src * 384;
  float4 a = s[2 * t], c = s[2 * t + 1];
  uint16_t o[8] = {f2b(a.x), f2b(a.y), f2b(a.z), f2b(a.w),
                   f2b(c.x), f2b(c.y), f2b(c.z), f2b(c.w)};
  ((uint4*)(wp + (size_t)row * 1536))[t] = *(const uint4*)o;
  if (t == 0) bp[row] = f2b(b[src]);
}

// async global->LDS, 16B per lane (m97/m104).
__device__ __forceinline__ void async_copy16(const uint16_t* g, uint16_t* l) {
  __builtin_amdgcn_global_load_lds(
      (const __attribute__((address_space(1))) void*)g,
      (__attribute__((address_space(3))) void*)l,
      16, 0, 0);
}

// C[M,N] = A[M,K] @ W[N,K]^T + bias[N]; bf16 in, fp32 accum (m97 structure).
// A row stride = lda (>= K) so A can be a column-slice of a fused buffer.
template <bool F32OUT>
__global__ __launch_bounds__(256) void gemm_bt_bias(
    const uint16_t* __restrict__ A, int lda,
    const uint16_t* __restrict__ W,
    const uint16_t* __restrict__ bias, void* __restrict__ Cout,
    int N, int K)
{
  __shared__ uint16_t As[128 * 64];
  __shared__ uint16_t Bs[128 * 64];
  const int tid  = threadIdx.x;
  const int lane = tid & 63;
  const int wave = tid >> 6;
  const int wm = (wave >> 1) * 64;
  const int wn = (wave & 1) * 64;
  const int bm = blockIdx.y * 128;
  const int bn = blockIdx.x * 128;
  const int ml = lane & 15;
  const int quad = lane >> 4;

  floatx4 acc[4][4];
#pragma unroll
  for (int i = 0; i < 4; ++i)
#pragma unroll
    for (int j = 0; j < 4; ++j)
      acc[i][j] = (floatx4){0.f, 0.f, 0.f, 0.f};

  const int srow = tid >> 3;        // 0..31
  const int scol = (tid & 7) * 8;   // 0..56
  const uint16_t* Ag = A + (size_t)(bm + srow) * lda + scol;
  const uint16_t* Wg = W + (size_t)(bn + srow) * K + scol;

  for (int k0 = 0; k0 < K; k0 += 64) {
#pragma unroll
    for (int r = 0; r < 4; ++r) {
      async_copy16(Ag + (size_t)r * 32 * lda + k0, &As[r * 2048 + tid * 8]);
      async_copy16(Wg + (size_t)r * 32 * K + k0, &Bs[r * 2048 + tid * 8]);
    }
    __syncthreads();
#pragma unroll
    for (int ks = 0; ks < 2; ++ks) {
      short8 a[4], b[4];
#pragma unroll
      for (int i = 0; i < 4; ++i)
        a[i] = *(const short8*)&As[(wm + i * 16 + ml) * 64 + ks * 32 + quad * 8];
#pragma unroll
      for (int j = 0; j < 4; ++j)
        b[j] = *(const short8*)&Bs[(wn + j * 16 + ml) * 64 + ks * 32 + quad * 8];
#pragma unroll
      for (int i = 0; i < 4; ++i)
#pragma unroll
        for (int j = 0; j < 4; ++j)
          acc[i][j] = __builtin_amdgcn_mfma_f32_16x16x32_bf16(a[i], b[j], acc[i][j], 0, 0, 0);
    }
    __syncthreads();
  }

  // C/D layout: col = lane&15, row = quad*4 + reg (m89/m91)
#pragma unroll
  for (int j = 0; j < 4; ++j) {
    const int col = bn + wn + j * 16 + ml;
    const float bv = b2f(bias[col]);
#pragma unroll
    for (int i = 0; i < 4; ++i) {
      const int row0 = bm + wm + i * 16 + quad * 4;
      if constexpr (F32OUT) {
        float* C32 = (float*)Cout;
#pragma unroll
        for (int r = 0; r < 4; ++r)
          C32[(size_t)(row0 + r) * N + col] = acc[i][j][r] + bv;
      } else {
        uint16_t* C = (uint16_t*)Cout;
#pragma unroll
        for (int r = 0; r < 4; ++r)
          C[(size_t)(row0 + r) * N + col] = f2b(acc[i][j][r] + bv);
      }
    }
  }
}

// Dual RMSNorm over a fused [T, 2048] buffer: cols 0..1535 normalized with wq
// (L=1536), cols 1536..2047 with wkv (L=512). In place. One row per block.
__global__ __launch_bounds__(256) void rmsnorm_dual(uint16_t* __restrict__ x,
                                                    const uint16_t* __restrict__ wq,
                                                    const uint16_t* __restrict__ wkv)
{
  __shared__ float red[4];
  __shared__ float invs[2];
  const int t = threadIdx.x;
  const int lane = t & 63;
  const int wave = t >> 6;          // waves 0-2: q segment; wave 3: kv segment
  uint16_t* xr = x + (size_t)blockIdx.x * 2048;

  uint4 v = ((const uint4*)xr)[t];
  const uint16_t* u = (const uint16_t*)&v;
  float lv[8];
  float ss = 0.f;
#pragma unroll
  for (int i = 0; i < 8; ++i) { lv[i] = b2f(u[i]); ss += lv[i] * lv[i]; }
#pragma unroll
  for (int o = 32; o >= 1; o >>= 1) ss += __shfl_down(ss, o, 64);
  if (lane == 0) red[wave] = ss;
  __syncthreads();
  if (t == 0)
    invs[0] = rsqrtf((red[0] + red[1] + red[2]) * (1.f / 1536.f) + 1.1920929e-7f);
  if (t == 64)
    invs[1] = rsqrtf(red[3] * (1.f / 512.f) + 1.1920929e-7f);
  __syncthreads();

  const float inv = (t < 192) ? invs[0] : invs[1];
  const uint16_t* wsrc = (t < 192) ? (wq + t * 8) : (wkv + (t - 192) * 8);
  uint4 wv = *(const uint4*)wsrc;
  const uint16_t* wu = (const uint16_t*)&wv;
  uint16_t ob[8];
#pragma unroll
  for (int i = 0; i < 8; ++i) ob[i] = f2b(lv[i] * inv * b2f(wu[i]));
  ((uint4*)xr)[t] = *(const uint4*)ob;
}

// Per-token head-vs-head attention; RoPE drops out of softmax (k_pe broadcast
// over g => per-h additive constant). qn:[T,2048] kvb:[T,4096] out:[T,2048]
__global__ __launch_bounds__(256) void attn_kernel(
    const uint16_t* __restrict__ qn,
    const uint16_t* __restrict__ kvb,
    uint16_t* __restrict__ outp)
{
  __shared__ uint16_t q_s[2048];
  __shared__ uint16_t kv_s[16 * 264];
  __shared__ float s_at[256];
  const int t = blockIdx.x;
  const int tid = threadIdx.x;

  ((uint4*)q_s)[tid] = ((const uint4*)(qn + (size_t)t * 2048))[tid];
  {
    const uint4* src = (const uint4*)(kvb + (size_t)t * 4096);
#pragma unroll
    for (int r = 0; r < 2; ++r) {
      int c = tid + r * 256;
      ((uint4*)kv_s)[(c >> 5) * 33 + (c & 31)] = src[c];
    }
  }
  __syncthreads();

  const int h = tid >> 4, g = tid & 15;
  float sc = 0.f;
  const uint4* qh = (const uint4*)(q_s + h * 128);
  const uint4* kg = (const uint4*)(kv_s + g * 264);
#pragma unroll
  for (int c = 0; c < 16; ++c) {
    uint4 qa = qh[c], kb = kg[c];
    const uint16_t* qa_u = (const uint16_t*)&qa;
    const uint16_t* kb_u = (const uint16_t*)&kb;
#pragma unroll
    for (int i = 0; i < 8; ++i) sc += b2f(qa_u[i]) * b2f(kb_u[i]);
  }
  sc *= 0.07216878364870323f;   // (128+64)^-0.5
  float mx = sc;
#pragma unroll
  for (int o = 8; o >= 1; o >>= 1) mx = fmaxf(mx, __shfl_xor(mx, o, 16));
  const float e = __expf(sc - mx);
  float sum = e;
#pragma unroll
  for (int o = 8; o >= 1; o >>= 1) sum += __shfl_xor(sum, o, 16);
  s_at[tid] = e / sum;
  __syncthreads();

  float acc[8] = {0.f, 0.f, 0.f, 0.f, 0.f, 0.f, 0.f, 0.f};
  const int c8 = tid & 15;
#pragma unroll
  for (int gg = 0; gg < 16; ++gg) {
    const float a = s_at[h * 16 + gg];
    uint4 vv = *(const uint4*)(kv_s + gg * 264 + 128 + c8 * 8);
    const uint16_t* vu = (const uint16_t*)&vv;
#pragma unroll
    for (int i = 0; i < 8; ++i) acc[i] += a * b2f(vu[i]);
  }
  uint16_t ob[8];
#pragma unroll
  for (int i = 0; i < 8; ++i) ob[i] = f2b(acc[i]);
  *(uint4*)(outp + (size_t)t * 2048 + h * 128 + c8 * 8) = *(const uint4*)ob;
}

extern "C" void kernel_launch(void* const* d_in, const int* in_sizes, int n_in,
                              void* d_out, int out_size, void* d_ws, size_t ws_size,
                              hipStream_t stream)
{
  (void)in_sizes; (void)n_in; (void)out_size; (void)ws_size;
  const float* x_r       = (const float*)d_in[0];
  const float* wq_a_w_r  = (const float*)d_in[3];
  const float* wq_a_b_r  = (const float*)d_in[4];
  const float* q_norm_r  = (const float*)d_in[5];
  const float* wq_b_w_r  = (const float*)d_in[6];
  const float* wq_b_b_r  = (const float*)d_in[7];
  const float* wkv_a_w_r = (const float*)d_in[8];
  const float* wkv_a_b_r = (const float*)d_in[9];
  const float* kv_norm_r = (const float*)d_in[10];
  const float* wkv_b_w_r = (const float*)d_in[11];
  const float* wkv_b_b_r = (const float*)d_in[12];
  const float* wo_w_r    = (const float*)d_in[13];
  const float* wo_b_r    = (const float*)d_in[14];

  char* ws = (char*)d_ws;
  uint16_t* cx     = (uint16_t*)(ws);                 // 8192x2048 bf16 x; reused for attn out
  uint16_t* cwf    = (uint16_t*)(ws + 33554432);      // fused [wq_a(1536); wkv_a[0:512]] x2048
  uint16_t* wpack  = (uint16_t*)(ws + 41943040);      // 2048x1536
  uint16_t* cwkv_b = (uint16_t*)(ws + 48234496);      // 4096x512
  uint16_t* cwo    = (uint16_t*)(ws + 52428800);      // 2048x2048
  char*     smallb = ws + 60817408;
  uint16_t* bfused = (uint16_t*)(smallb);             // 2048 = bq_a(1536)||bkv_a(512)
  uint16_t* qnorm  = (uint16_t*)(smallb + 8192);      // 1536
  uint16_t* kvnorm = (uint16_t*)(smallb + 16384);     // 512
  uint16_t* bkv_b  = (uint16_t*)(smallb + 24576);     // 4096
  uint16_t* bwo    = (uint16_t*)(smallb + 40960);     // 2048
  uint16_t* bpack  = (uint16_t*)(smallb + 49152);     // 2048
  uint16_t* qakva  = (uint16_t*)(ws + 60882944);      // 8192x2048 (qa||kva per row)
  uint16_t* qn     = (uint16_t*)(ws + 94437376);      // 8192x2048
  uint16_t* kvb    = (uint16_t*)(ws + 127991808);     // 8192x4096  (end ~186 MiB)
  uint16_t* attn   = cx;                              // cx dead after fused GEMM1

  // conversions (fp32 -> bf16)
  cvt_w<<<8192, 256, 0, stream>>>(x_r,       cx,               2097152);
  cvt_w<<<1536, 256, 0, stream>>>(wq_a_w_r,  cwf,              393216);
  cvt_w<<<512,  256, 0, stream>>>(wkv_a_w_r, cwf + 1536*2048,  131072);  // first 512 rows only (k_pe dead)
  cvt_w<<<1024, 256, 0, stream>>>(wkv_b_w_r, cwkv_b,           262144);
  cvt_w<<<2048, 256, 0, stream>>>(wo_w_r,    cwo,              524288);
  cvt_small6<<<6, 256, 0, stream>>>(wq_a_b_r, bfused, wkv_a_b_r, bfused + 1536,
                                    q_norm_r, qnorm, kv_norm_r, kvnorm,
                                    wkv_b_b_r, bkv_b, wo_b_r, bwo);
  pack_wq<<<2048, 192, 0, stream>>>(wq_b_w_r, wq_b_b_r, wpack, bpack);

  // fused q_a + kv_a projection: [8192,2048] = x @ [wq_a; wkv_a[0:512]]^T
  gemm_bt_bias<false><<<dim3(16, 64), 256, 0, stream>>>(cx, 2048, cwf, bfused, qakva, 2048, 2048);
  rmsnorm_dual<<<8192, 256, 0, stream>>>(qakva, qnorm, kvnorm);
  gemm_bt_bias<false><<<dim3(16, 64), 256, 0, stream>>>(qakva, 2048, wpack, bpack, qn, 2048, 1536);
  gemm_bt_bias<false><<<dim3(32, 64), 256, 0, stream>>>(qakva + 1536, 2048, cwkv_b, bkv_b, kvb, 4096, 512);
  attn_kernel<<<8192, 256, 0, stream>>>(qn, kvb, attn);
  gemm_bt_bias<true><<<dim3(16, 64), 256, 0, stream>>>(attn, 2048, cwo, bwo, d_out, 2048, 2048);
}